// Round 4
// baseline (213.297 us; speedup 1.0000x reference)
//
#include <hip/hip_runtime.h>
#include <hip/hip_bf16.h>
#include <math.h>

typedef __attribute__((ext_vector_type(8))) short bf16x8;
typedef __attribute__((ext_vector_type(4))) float f32x4;

#define NROWS 8192
#define DIM   768
#define BM    128
#define BN    128
#define BK    64

// ---- float <-> order-preserving uint key (for atomicMax on floats) ----
__device__ inline unsigned fkey(float v) {
  unsigned u = __float_as_uint(v);
  return (u & 0x80000000u) ? ~u : (u | 0x80000000u);
}
__device__ inline float funkey(unsigned k) {
  unsigned u = (k & 0x80000000u) ? (k & 0x7fffffffu) : ~k;
  return __uint_as_float(u);
}

// ---- kernel 1: row-normalize ex,ey -> bf16 matrices in workspace ----
__global__ __launch_bounds__(256) void normalize_kernel(
    const float* __restrict__ ex, const float* __restrict__ ey,
    __hip_bfloat16* __restrict__ An, __hip_bfloat16* __restrict__ Bn) {
  int row = blockIdx.x;  // 0..16383: first 8192 = ex, rest = ey
  const float* src;
  __hip_bfloat16* dst;
  if (row < NROWS) {
    src = ex + (size_t)row * DIM;
    dst = An + (size_t)row * DIM;
  } else {
    src = ey + (size_t)(row - NROWS) * DIM;
    dst = Bn + (size_t)(row - NROWS) * DIM;
  }
  int t = threadIdx.x;
  float x0 = src[t], x1 = src[t + 256], x2 = src[t + 512];
  float ss = x0 * x0 + x1 * x1 + x2 * x2;
#pragma unroll
  for (int s = 1; s < 64; s <<= 1) ss += __shfl_xor(ss, s);
  __shared__ float wsum[4];
  if ((t & 63) == 0) wsum[t >> 6] = ss;
  __syncthreads();
  float tot = wsum[0] + wsum[1] + wsum[2] + wsum[3];
  float scale = 1.0f / fmaxf(sqrtf(tot), 1e-8f);
  dst[t]       = __float2bfloat16(x0 * scale);
  dst[t + 256] = __float2bfloat16(x1 * scale);
  dst[t + 512] = __float2bfloat16(x2 * scale);
}

// ---- kernel 2: fused C = An*Bn^T with in-register row/col max reduction ----
// 256 threads = 4 waves in 2x2; each wave owns a 64x64 output sub-tile
// (4x4 fragments of 16x16). LDS tiles 128x64 bf16 (128B rows), XOR-swizzled
// (slot ^= row&7) so ds_read_b128 fragment reads are bank-conflict-free.
// Staging: global_load_lds width=16 with pre-swizzled global source (linear
// LDS dest as hardware requires).
__global__ __launch_bounds__(256, 2) void gemm_max_kernel(
    const __hip_bfloat16* __restrict__ A, const __hip_bfloat16* __restrict__ B,
    unsigned* __restrict__ rowKey, unsigned* __restrict__ colKey) {
  __shared__ short As[BM * BK];
  __shared__ short Bs[BN * BK];
  const int t = threadIdx.x;
  const int lane = t & 63;
  const int wid = t >> 6;
  const int wr = wid >> 1, wc = wid & 1;
  const int brow = blockIdx.x * BM;
  const int bcol = blockIdx.y * BN;
  const int l15 = lane & 15, l4 = lane >> 4;

  f32x4 acc[4][4];
#pragma unroll
  for (int m = 0; m < 4; ++m)
#pragma unroll
    for (int n = 0; n < 4; ++n) acc[m][n] = (f32x4)0.0f;

  for (int k0 = 0; k0 < DIM; k0 += BK) {
    __syncthreads();  // previous-iter LDS reads done
#pragma unroll
    for (int p = 0; p < 4; ++p) {
      int L = p * 4096 + t * 16;        // linear LDS byte offset
      int r = L >> 7;                   // tile row 0..127
      int sl = (L >> 4) & 7;            // linear 16B slot within row
      int ssl = sl ^ (r & 7);           // pre-swizzled source slot
      const char* ga = (const char*)(A + (size_t)(brow + r) * DIM + k0) + ssl * 16;
      const char* gb = (const char*)(B + (size_t)(bcol + r) * DIM + k0) + ssl * 16;
      __builtin_amdgcn_global_load_lds(
          (const __attribute__((address_space(1))) void*)ga,
          (__attribute__((address_space(3))) void*)((char*)As + L), 16, 0, 0);
      __builtin_amdgcn_global_load_lds(
          (const __attribute__((address_space(1))) void*)gb,
          (__attribute__((address_space(3))) void*)((char*)Bs + L), 16, 0, 0);
    }
    __syncthreads();  // staging complete (compiler drains vmcnt before barrier)
#pragma unroll
    for (int kk = 0; kk < 2; ++kk) {
      bf16x8 af[4], bfr[4];
#pragma unroll
      for (int m = 0; m < 4; ++m) {
        int r = wr * 64 + m * 16 + l15;
        int q = kk * 4 + l4;
        int off = r * 128 + ((q ^ (r & 7)) << 4);
        af[m] = *(const bf16x8*)((const char*)As + off);
      }
#pragma unroll
      for (int n = 0; n < 4; ++n) {
        int r = wc * 64 + n * 16 + l15;
        int q = kk * 4 + l4;
        int off = r * 128 + ((q ^ (r & 7)) << 4);
        bfr[n] = *(const bf16x8*)((const char*)Bs + off);
      }
#pragma unroll
      for (int m = 0; m < 4; ++m)
#pragma unroll
        for (int n = 0; n < 4; ++n)
          acc[m][n] = __builtin_amdgcn_mfma_f32_16x16x32_bf16(
              af[m], bfr[n], acc[m][n], 0, 0, 0);
    }
  }

  // ---- epilogue: row/col maxes of this block's 128x128 tile ----
  // D layout (16x16x32 bf16): col = lane&15, row = (lane>>4)*4 + reg
#pragma unroll
  for (int m = 0; m < 4; ++m) {
#pragma unroll
    for (int j = 0; j < 4; ++j) {
      float v = fmaxf(fmaxf(acc[m][0][j], acc[m][1][j]),
                      fmaxf(acc[m][2][j], acc[m][3][j]));
#pragma unroll
      for (int s = 1; s < 16; s <<= 1) v = fmaxf(v, __shfl_xor(v, s));
      if (l15 == 0) {
        int grow = brow + wr * 64 + m * 16 + l4 * 4 + j;
        atomicMax(&rowKey[grow], fkey(v));
      }
    }
  }
#pragma unroll
  for (int n = 0; n < 4; ++n) {
    float v = -1e30f;
#pragma unroll
    for (int m = 0; m < 4; ++m)
#pragma unroll
      for (int j = 0; j < 4; ++j) v = fmaxf(v, acc[m][n][j]);
    v = fmaxf(v, __shfl_xor(v, 16));
    v = fmaxf(v, __shfl_xor(v, 32));
    if (l4 == 0) {
      int gcol = bcol + wc * 64 + n * 16 + l15;
      atomicMax(&colKey[gcol], fkey(v));
    }
  }
}

// ---- kernel 3: entropy terms from the max arrays ----
__global__ __launch_bounds__(256) void finalize_kernel(
    const unsigned* __restrict__ rowKey, const unsigned* __restrict__ colKey,
    float* __restrict__ out) {
  const unsigned* src = (blockIdx.x == 0) ? rowKey : colKey;
  int t = threadIdx.x;
  const float log_norm = -0.6957949819f;  // -log(0.8) - 0.5*log(2*pi)
  float s = 0.0f;
  for (int i = t; i < NROWS; i += 256) {
    float c = funkey(src[i]);
    float lp = -(c * c) * 0.78125f + log_norm;  // 1/(2*0.8^2) = 0.78125
    s += __expf(lp) * lp;
  }
#pragma unroll
  for (int sh = 1; sh < 64; sh <<= 1) s += __shfl_xor(s, sh);
  __shared__ float wsum[4];
  if ((t & 63) == 0) wsum[t >> 6] = s;
  __syncthreads();
  if (t == 0) out[blockIdx.x] = -(wsum[0] + wsum[1] + wsum[2] + wsum[3]);
}

extern "C" void kernel_launch(void* const* d_in, const int* in_sizes, int n_in,
                              void* d_out, int out_size, void* d_ws, size_t ws_size,
                              hipStream_t stream) {
  const float* ex = (const float*)d_in[0];
  const float* ey = (const float*)d_in[1];
  char* ws = (char*)d_ws;
  __hip_bfloat16* An = (__hip_bfloat16*)ws;                              // 12.6 MB
  __hip_bfloat16* Bn = (__hip_bfloat16*)(ws + (size_t)NROWS * DIM * 2);  // 12.6 MB
  unsigned* rowKey = (unsigned*)(ws + (size_t)NROWS * DIM * 4);          // 32 KB
  unsigned* colKey = rowKey + NROWS;                                     // 32 KB

  hipMemsetAsync(rowKey, 0, 2 * NROWS * sizeof(unsigned), stream);
  normalize_kernel<<<2 * NROWS, 256, 0, stream>>>(ex, ey, An, Bn);
  dim3 grid(NROWS / BM, NROWS / BN);
  gemm_max_kernel<<<grid, 256, 0, stream>>>(An, Bn, rowKey, colKey);
  finalize_kernel<<<2, 256, 0, stream>>>(rowKey, colKey, (float*)d_out);
}

// Round 5
// 205.715 us; speedup vs baseline: 1.0369x; 1.0369x over previous
//
#include <hip/hip_runtime.h>
#include <hip/hip_bf16.h>
#include <math.h>

typedef __attribute__((ext_vector_type(8))) short bf16x8;
typedef __attribute__((ext_vector_type(4))) float f32x4;

#define NROWS 8192
#define DIM   768
#define BM    256
#define BN    256
#define BK    64
#define NT    12   // DIM / BK, must be even

// ---- float <-> order-preserving uint key (for atomicMax on floats) ----
__device__ inline unsigned fkey(float v) {
  unsigned u = __float_as_uint(v);
  return (u & 0x80000000u) ? ~u : (u | 0x80000000u);
}
__device__ inline float funkey(unsigned k) {
  unsigned u = (k & 0x80000000u) ? (k & 0x7fffffffu) : ~k;
  return __uint_as_float(u);
}

// ---- kernel 1: row-normalize ex,ey -> bf16 matrices in workspace ----
__global__ __launch_bounds__(256) void normalize_kernel(
    const float* __restrict__ ex, const float* __restrict__ ey,
    __hip_bfloat16* __restrict__ An, __hip_bfloat16* __restrict__ Bn) {
  int row = blockIdx.x;  // 0..16383: first 8192 = ex, rest = ey
  const float* src;
  __hip_bfloat16* dst;
  if (row < NROWS) {
    src = ex + (size_t)row * DIM;
    dst = An + (size_t)row * DIM;
  } else {
    src = ey + (size_t)(row - NROWS) * DIM;
    dst = Bn + (size_t)(row - NROWS) * DIM;
  }
  int t = threadIdx.x;
  float x0 = src[t], x1 = src[t + 256], x2 = src[t + 512];
  float ss = x0 * x0 + x1 * x1 + x2 * x2;
#pragma unroll
  for (int s = 1; s < 64; s <<= 1) ss += __shfl_xor(ss, s);
  __shared__ float wsum[4];
  if ((t & 63) == 0) wsum[t >> 6] = ss;
  __syncthreads();
  float tot = wsum[0] + wsum[1] + wsum[2] + wsum[3];
  float scale = 1.0f / fmaxf(sqrtf(tot), 1e-8f);
  dst[t]       = __float2bfloat16(x0 * scale);
  dst[t + 256] = __float2bfloat16(x1 * scale);
  dst[t + 512] = __float2bfloat16(x2 * scale);
}

// ---- kernel 2: 256x256-tile 8-phase fused GEMM + row/col max -------------
// 512 threads = 8 waves (2 row-groups x 4 col-groups); per-wave 128x64 output.
// LDS: [2 buf][A|B][2 K-half][256 rows][64 B].  A K-half region is read only
// during its 2 phases (kk fixed per phase), so it is free for restaging 2+
// phases later.  Stage ledger (iter computes tiles t,t+1; all stages 2 calls):
//   ph1:A(t+1,1) ph2:B(t+1,1) ph3:A(t+2,0) ph4:B(t+2,0)+vmcnt(4)
//   ph5:A(t+2,1) ph6:B(t+2,1) ph7:A(t+3,0) ph8:B(t+3,0)+vmcnt(4)
// Every read's staging is complete at the preceding vmcnt(4); no vmcnt(0)
// in the main loop (T3+T4).  Swizzle: 16B slot = l4 ^ ((row>>1)&3) (64B rows).
__global__ __launch_bounds__(512, 2) void gemm_max_kernel(
    const __hip_bfloat16* __restrict__ A, const __hip_bfloat16* __restrict__ B,
    unsigned* __restrict__ rowKey, unsigned* __restrict__ colKey) {
  __shared__ __align__(16) char lds[131072];
  const int t = threadIdx.x;
  const int lane = t & 63;
  const int wid = t >> 6;       // 0..7
  const int wr = wid >> 2;      // 0..1
  const int wc = wid & 3;       // 0..3
  const int brow = blockIdx.x * BM;
  const int bcol = blockIdx.y * BN;
  const int l15 = lane & 15, l4 = lane >> 4;

  // stage one K-half of one matrix for tile tt: 16 KB = 2 x (512 thr x 16 B)
  auto stage_ = [&](int mat, int tt, int kh) {
    char* base = lds + ((tt & 1) << 16) + (mat << 15) + (kh << 14);
    const __hip_bfloat16* G = mat ? B : A;
    const int bb = mat ? bcol : brow;
#pragma unroll
    for (int c = 0; c < 2; ++c) {
      int L = c * 8192 + t * 16;          // linear LDS byte offset in region
      int r = L >> 6;                     // row 0..255
      int sl = (L >> 4) & 3;              // linear 16B slot
      int ssl = sl ^ ((r >> 1) & 3);      // pre-swizzled source slot
      const __hip_bfloat16* g =
          G + (size_t)(bb + r) * DIM + tt * BK + kh * 32 + ssl * 8;
      __builtin_amdgcn_global_load_lds(
          (const __attribute__((address_space(1))) void*)g,
          (__attribute__((address_space(3))) void*)(base + L), 16, 0, 0);
    }
  };

  f32x4 acc[8][4];
#pragma unroll
  for (int m = 0; m < 8; ++m)
#pragma unroll
    for (int n = 0; n < 4; ++n) acc[m][n] = (f32x4)0.0f;
  bf16x8 bfr[4];

#define PHASE(TT, KK, OH, DOWAIT, ...)                                         \
  do {                                                                         \
    const char* regA_ = lds + (((TT) & 1) << 16) + ((KK) << 14);               \
    const char* regB_ = regA_ + 32768;                                         \
    bf16x8 af[4];                                                              \
    _Pragma("unroll") for (int m_ = 0; m_ < 4; ++m_) {                         \
      int r_ = wr * 128 + ((OH) * 4 + m_) * 16 + l15;                          \
      af[m_] = *(const bf16x8*)(regA_ + r_ * 64 +                              \
                                ((l4 ^ ((r_ >> 1) & 3)) << 4));                \
    }                                                                          \
    if ((OH) == 0) {                                                           \
      _Pragma("unroll") for (int n_ = 0; n_ < 4; ++n_) {                       \
        int r_ = wc * 64 + n_ * 16 + l15;                                      \
        bfr[n_] = *(const bf16x8*)(regB_ + r_ * 64 +                           \
                                   ((l4 ^ ((r_ >> 1) & 3)) << 4));             \
      }                                                                        \
    }                                                                          \
    __VA_ARGS__;                                                               \
    if (DOWAIT) asm volatile("s_waitcnt vmcnt(4)" ::: "memory");               \
    __builtin_amdgcn_s_barrier();                                              \
    asm volatile("s_waitcnt lgkmcnt(0)" ::: "memory");                         \
    __builtin_amdgcn_sched_barrier(0);                                         \
    __builtin_amdgcn_s_setprio(1);                                             \
    _Pragma("unroll") for (int m_ = 0; m_ < 4; ++m_)                           \
      _Pragma("unroll") for (int n_ = 0; n_ < 4; ++n_)                         \
        acc[(OH) * 4 + m_][n_] = __builtin_amdgcn_mfma_f32_16x16x32_bf16(      \
            af[m_], bfr[n_], acc[(OH) * 4 + m_][n_], 0, 0, 0);                 \
    __builtin_amdgcn_s_setprio(0);                                             \
    __builtin_amdgcn_s_barrier();                                              \
  } while (0)

  // prologue: tile0 fully + tile1 K-half0; wait so tile0 is resident
  stage_(0, 0, 0); stage_(1, 0, 0);
  stage_(0, 0, 1); stage_(1, 0, 1);
  stage_(0, 1, 0); stage_(1, 1, 0);
  asm volatile("s_waitcnt vmcnt(4)" ::: "memory");
  __builtin_amdgcn_s_barrier();

  for (int t0 = 0; t0 < NT; t0 += 2) {
    PHASE(t0,     0, 0, 0, stage_(0, t0 + 1, 1));
    PHASE(t0,     0, 1, 0, stage_(1, t0 + 1, 1));
    PHASE(t0,     1, 0, 0, if (t0 + 2 < NT) stage_(0, t0 + 2, 0));
    PHASE(t0,     1, 1, 1, if (t0 + 2 < NT) stage_(1, t0 + 2, 0));
    PHASE(t0 + 1, 0, 0, 0, if (t0 + 2 < NT) stage_(0, t0 + 2, 1));
    PHASE(t0 + 1, 0, 1, 0, if (t0 + 2 < NT) stage_(1, t0 + 2, 1));
    PHASE(t0 + 1, 1, 0, 0, if (t0 + 3 < NT) stage_(0, t0 + 3, 0));
    PHASE(t0 + 1, 1, 1, 1, if (t0 + 3 < NT) stage_(1, t0 + 3, 0));
  }
#undef PHASE

  // ---- epilogue: row/col maxes of this block's 256x256 tile ----
  // D layout (16x16x32 bf16): col = lane&15, row = (lane>>4)*4 + reg
#pragma unroll
  for (int m = 0; m < 8; ++m) {
#pragma unroll
    for (int j = 0; j < 4; ++j) {
      float v = fmaxf(fmaxf(acc[m][0][j], acc[m][1][j]),
                      fmaxf(acc[m][2][j], acc[m][3][j]));
#pragma unroll
      for (int s = 1; s < 16; s <<= 1) v = fmaxf(v, __shfl_xor(v, s));
      if (l15 == 0) {
        int grow = brow + wr * 128 + m * 16 + l4 * 4 + j;
        atomicMax(&rowKey[grow], fkey(v));
      }
    }
  }
#pragma unroll
  for (int n = 0; n < 4; ++n) {
    float v = -1e30f;
#pragma unroll
    for (int m = 0; m < 8; ++m)
#pragma unroll
      for (int j = 0; j < 4; ++j) v = fmaxf(v, acc[m][n][j]);
    v = fmaxf(v, __shfl_xor(v, 16));
    v = fmaxf(v, __shfl_xor(v, 32));
    if (l4 == 0) {
      int gcol = bcol + wc * 64 + n * 16 + l15;
      atomicMax(&colKey[gcol], fkey(v));
    }
  }
}

// ---- kernel 3: entropy terms from the max arrays ----
__global__ __launch_bounds__(256) void finalize_kernel(
    const unsigned* __restrict__ rowKey, const unsigned* __restrict__ colKey,
    float* __restrict__ out) {
  const unsigned* src = (blockIdx.x == 0) ? rowKey : colKey;
  int t = threadIdx.x;
  const float log_norm = -0.6957949819f;  // -log(0.8) - 0.5*log(2*pi)
  float s = 0.0f;
  for (int i = t; i < NROWS; i += 256) {
    float c = funkey(src[i]);
    float lp = -(c * c) * 0.78125f + log_norm;  // 1/(2*0.8^2) = 0.78125
    s += __expf(lp) * lp;
  }
#pragma unroll
  for (int sh = 1; sh < 64; sh <<= 1) s += __shfl_xor(s, sh);
  __shared__ float wsum[4];
  if ((t & 63) == 0) wsum[t >> 6] = s;
  __syncthreads();
  if (t == 0) out[blockIdx.x] = -(wsum[0] + wsum[1] + wsum[2] + wsum[3]);
}

extern "C" void kernel_launch(void* const* d_in, const int* in_sizes, int n_in,
                              void* d_out, int out_size, void* d_ws, size_t ws_size,
                              hipStream_t stream) {
  const float* ex = (const float*)d_in[0];
  const float* ey = (const float*)d_in[1];
  char* ws = (char*)d_ws;
  __hip_bfloat16* An = (__hip_bfloat16*)ws;                              // 12.6 MB
  __hip_bfloat16* Bn = (__hip_bfloat16*)(ws + (size_t)NROWS * DIM * 2);  // 12.6 MB
  unsigned* rowKey = (unsigned*)(ws + (size_t)NROWS * DIM * 4);          // 32 KB
  unsigned* colKey = rowKey + NROWS;                                     // 32 KB

  hipMemsetAsync(rowKey, 0, 2 * NROWS * sizeof(unsigned), stream);
  normalize_kernel<<<2 * NROWS, 256, 0, stream>>>(ex, ey, An, Bn);
  dim3 grid(NROWS / BM, NROWS / BN);
  gemm_max_kernel<<<grid, 512, 0, stream>>>(An, Bn, rowKey, colKey);
  finalize_kernel<<<2, 256, 0, stream>>>(rowKey, colKey, (float*)d_out);
}

// Round 6
// 205.355 us; speedup vs baseline: 1.0387x; 1.0018x over previous
//
#include <hip/hip_runtime.h>
#include <hip/hip_bf16.h>
#include <math.h>

typedef __attribute__((ext_vector_type(8))) short bf16x8;
typedef __attribute__((ext_vector_type(4))) float f32x4;

#define NROWS 8192
#define DIM   768
#define BM    256
#define BN    256
#define BK    64
#define NT    12   // DIM / BK, must be even

// ---- float <-> order-preserving uint key (for atomicMax on floats) ----
__device__ inline unsigned fkey(float v) {
  unsigned u = __float_as_uint(v);
  return (u & 0x80000000u) ? ~u : (u | 0x80000000u);
}
__device__ inline float funkey(unsigned k) {
  unsigned u = (k & 0x80000000u) ? (k & 0x7fffffffu) : ~k;
  return __uint_as_float(u);
}

// ---- kernel 1: row-normalize ex,ey -> bf16 matrices in workspace ----
__global__ __launch_bounds__(256) void normalize_kernel(
    const float* __restrict__ ex, const float* __restrict__ ey,
    __hip_bfloat16* __restrict__ An, __hip_bfloat16* __restrict__ Bn) {
  int row = blockIdx.x;  // 0..16383: first 8192 = ex, rest = ey
  const float* src;
  __hip_bfloat16* dst;
  if (row < NROWS) {
    src = ex + (size_t)row * DIM;
    dst = An + (size_t)row * DIM;
  } else {
    src = ey + (size_t)(row - NROWS) * DIM;
    dst = Bn + (size_t)(row - NROWS) * DIM;
  }
  int t = threadIdx.x;
  float x0 = src[t], x1 = src[t + 256], x2 = src[t + 512];
  float ss = x0 * x0 + x1 * x1 + x2 * x2;
#pragma unroll
  for (int s = 1; s < 64; s <<= 1) ss += __shfl_xor(ss, s);
  __shared__ float wsum[4];
  if ((t & 63) == 0) wsum[t >> 6] = ss;
  __syncthreads();
  float tot = wsum[0] + wsum[1] + wsum[2] + wsum[3];
  float scale = 1.0f / fmaxf(sqrtf(tot), 1e-8f);
  dst[t]       = __float2bfloat16(x0 * scale);
  dst[t + 256] = __float2bfloat16(x1 * scale);
  dst[t + 512] = __float2bfloat16(x2 * scale);
}

// ---- kernel 2: 256x256-tile 8-phase fused GEMM + row/col max -------------
// 512 threads = 8 waves (2 row-groups x 4 col-groups); per-wave 128x64 output.
// LDS: [2 buf][A|B][2 K-half][256 rows][64 B].  Stage ledger (iter computes
// tiles t,t+1):
//   ph1:A(t+1,1) ph2:B(t+1,1) ph3:A(t+2,0) ph4:B(t+2,0)+vmcnt(4)
//   ph5:A(t+2,1) ph6:B(t+2,1) ph7:A(t+3,0) ph8:B(t+3,0)+vmcnt(4)
// vmcnt(4) at ph4 drains {prev ph7/8, ph1/2}; at ph8 drains {ph3..6}.  Every
// read's staging drains at a vmcnt+barrier at least one phase earlier.  ONE
// barrier per phase, AFTER the vmcnt: cross-wave visibility = (issuer drains
// via its vmcnt) -> barrier -> (reader reads).  Restage-vs-read safety: a
// region restaged at phase P was last read at phase P-2; the reader's lgkm
// waits (compiler fine-grained) complete before its MFMAs, hence before its
// barrier(P-1), hence before any wave issues the P stage.  Final iteration
// peeled with vmcnt(0) (steady-state vmcnt(4) under-drains when stages stop).
// No lgkmcnt(0)/sched_barrier before MFMA: ds_reads are compiler-visible, so
// fine-grained lgkm waits let MFMAs start as fragments land (read/MFMA
// overlap across waves).  Swizzle: 16B slot = l4 ^ ((row>>1)&3) (64B rows).
__global__ __launch_bounds__(512, 2) void gemm_max_kernel(
    const __hip_bfloat16* __restrict__ A, const __hip_bfloat16* __restrict__ B,
    unsigned* __restrict__ rowKey, unsigned* __restrict__ colKey) {
  __shared__ __align__(16) char lds[131072];
  const int t = threadIdx.x;
  const int lane = t & 63;
  const int wid = t >> 6;       // 0..7
  const int wr = wid >> 2;      // 0..1
  const int wc = wid & 3;       // 0..3
  const int brow = blockIdx.x * BM;
  const int bcol = blockIdx.y * BN;
  const int l15 = lane & 15, l4 = lane >> 4;

  // stage one K-half of one matrix for tile tt: 16 KB = 2 x (512 thr x 16 B)
  auto stage_ = [&](int mat, int tt, int kh) {
    char* base = lds + ((tt & 1) << 16) + (mat << 15) + (kh << 14);
    const __hip_bfloat16* G = mat ? B : A;
    const int bb = mat ? bcol : brow;
#pragma unroll
    for (int c = 0; c < 2; ++c) {
      int L = c * 8192 + t * 16;          // linear LDS byte offset in region
      int r = L >> 6;                     // row 0..255
      int sl = (L >> 4) & 3;              // linear 16B slot
      int ssl = sl ^ ((r >> 1) & 3);      // pre-swizzled source slot
      const __hip_bfloat16* g =
          G + (size_t)(bb + r) * DIM + tt * BK + kh * 32 + ssl * 8;
      __builtin_amdgcn_global_load_lds(
          (const __attribute__((address_space(1))) void*)g,
          (__attribute__((address_space(3))) void*)(base + L), 16, 0, 0);
    }
  };

  f32x4 acc[8][4];
#pragma unroll
  for (int m = 0; m < 8; ++m)
#pragma unroll
    for (int n = 0; n < 4; ++n) acc[m][n] = (f32x4)0.0f;
  bf16x8 bfr[4];

#define NOPW  do {} while (0)
#define VM4   asm volatile("s_waitcnt vmcnt(4)" ::: "memory")
#define VM0   asm volatile("s_waitcnt vmcnt(0)" ::: "memory")

#define PHASE(TT, KK, OH, STAGESTMT, WAITSTMT)                                 \
  do {                                                                         \
    const char* regA_ = lds + (((TT) & 1) << 16) + ((KK) << 14);               \
    const char* regB_ = regA_ + 32768;                                         \
    bf16x8 af[4];                                                              \
    _Pragma("unroll") for (int m_ = 0; m_ < 4; ++m_) {                         \
      int r_ = wr * 128 + ((OH) * 4 + m_) * 16 + l15;                          \
      af[m_] = *(const bf16x8*)(regA_ + r_ * 64 +                              \
                                ((l4 ^ ((r_ >> 1) & 3)) << 4));                \
    }                                                                          \
    if ((OH) == 0) {                                                           \
      _Pragma("unroll") for (int n_ = 0; n_ < 4; ++n_) {                       \
        int r_ = wc * 64 + n_ * 16 + l15;                                      \
        bfr[n_] = *(const bf16x8*)(regB_ + r_ * 64 +                           \
                                   ((l4 ^ ((r_ >> 1) & 3)) << 4));             \
      }                                                                        \
    }                                                                          \
    STAGESTMT;                                                                 \
    WAITSTMT;                                                                  \
    __builtin_amdgcn_s_setprio(1);                                             \
    _Pragma("unroll") for (int m_ = 0; m_ < 4; ++m_)                           \
      _Pragma("unroll") for (int n_ = 0; n_ < 4; ++n_)                         \
        acc[(OH) * 4 + m_][n_] = __builtin_amdgcn_mfma_f32_16x16x32_bf16(      \
            af[m_], bfr[n_], acc[(OH) * 4 + m_][n_], 0, 0, 0);                 \
    __builtin_amdgcn_s_setprio(0);                                             \
    __builtin_amdgcn_s_barrier();                                              \
  } while (0)

  // prologue: tile0 fully + tile1 K-half0; drain tile0, leave (1,0) in flight
  stage_(0, 0, 0); stage_(1, 0, 0);
  stage_(0, 0, 1); stage_(1, 0, 1);
  stage_(0, 1, 0); stage_(1, 1, 0);
  VM4;
  __builtin_amdgcn_s_barrier();

  for (int t0 = 0; t0 < NT - 2; t0 += 2) {
    PHASE(t0,     0, 0, stage_(0, t0 + 1, 1), NOPW);
    PHASE(t0,     0, 1, stage_(1, t0 + 1, 1), NOPW);
    PHASE(t0,     1, 0, stage_(0, t0 + 2, 0), NOPW);
    PHASE(t0,     1, 1, stage_(1, t0 + 2, 0), VM4);
    PHASE(t0 + 1, 0, 0, stage_(0, t0 + 2, 1), NOPW);
    PHASE(t0 + 1, 0, 1, stage_(1, t0 + 2, 1), NOPW);
    PHASE(t0 + 1, 1, 0, stage_(0, t0 + 3, 0), NOPW);
    PHASE(t0 + 1, 1, 1, stage_(1, t0 + 3, 0), VM4);
  }
  // peeled final iteration (t0 = NT-2): stages for (NT-1,1) only, full drain
  PHASE(NT - 2, 0, 0, stage_(0, NT - 1, 1), NOPW);
  PHASE(NT - 2, 0, 1, stage_(1, NT - 1, 1), NOPW);
  PHASE(NT - 2, 1, 0, NOPW, NOPW);
  PHASE(NT - 2, 1, 1, NOPW, VM0);
  PHASE(NT - 1, 0, 0, NOPW, NOPW);
  PHASE(NT - 1, 0, 1, NOPW, NOPW);
  PHASE(NT - 1, 1, 0, NOPW, NOPW);
  PHASE(NT - 1, 1, 1, NOPW, NOPW);
#undef PHASE
#undef NOPW
#undef VM4
#undef VM0

  // ---- epilogue: row/col maxes of this block's 256x256 tile ----
  // D layout (16x16x32 bf16): col = lane&15, row = (lane>>4)*4 + reg
#pragma unroll
  for (int m = 0; m < 8; ++m) {
#pragma unroll
    for (int j = 0; j < 4; ++j) {
      float v = fmaxf(fmaxf(acc[m][0][j], acc[m][1][j]),
                      fmaxf(acc[m][2][j], acc[m][3][j]));
#pragma unroll
      for (int s = 1; s < 16; s <<= 1) v = fmaxf(v, __shfl_xor(v, s));
      if (l15 == 0) {
        int grow = brow + wr * 128 + m * 16 + l4 * 4 + j;
        atomicMax(&rowKey[grow], fkey(v));
      }
    }
  }
#pragma unroll
  for (int n = 0; n < 4; ++n) {
    float v = -1e30f;
#pragma unroll
    for (int m = 0; m < 8; ++m)
#pragma unroll
      for (int j = 0; j < 4; ++j) v = fmaxf(v, acc[m][n][j]);
    v = fmaxf(v, __shfl_xor(v, 16));
    v = fmaxf(v, __shfl_xor(v, 32));
    if (l4 == 0) {
      int gcol = bcol + wc * 64 + n * 16 + l15;
      atomicMax(&colKey[gcol], fkey(v));
    }
  }
}

// ---- kernel 3: entropy terms from the max arrays ----
__global__ __launch_bounds__(256) void finalize_kernel(
    const unsigned* __restrict__ rowKey, const unsigned* __restrict__ colKey,
    float* __restrict__ out) {
  const unsigned* src = (blockIdx.x == 0) ? rowKey : colKey;
  int t = threadIdx.x;
  const float log_norm = -0.6957949819f;  // -log(0.8) - 0.5*log(2*pi)
  float s = 0.0f;
  for (int i = t; i < NROWS; i += 256) {
    float c = funkey(src[i]);
    float lp = -(c * c) * 0.78125f + log_norm;  // 1/(2*0.8^2) = 0.78125
    s += __expf(lp) * lp;
  }
#pragma unroll
  for (int sh = 1; sh < 64; sh <<= 1) s += __shfl_xor(s, sh);
  __shared__ float wsum[4];
  if ((t & 63) == 0) wsum[t >> 6] = s;
  __syncthreads();
  if (t == 0) out[blockIdx.x] = -(wsum[0] + wsum[1] + wsum[2] + wsum[3]);
}

extern "C" void kernel_launch(void* const* d_in, const int* in_sizes, int n_in,
                              void* d_out, int out_size, void* d_ws, size_t ws_size,
                              hipStream_t stream) {
  const float* ex = (const float*)d_in[0];
  const float* ey = (const float*)d_in[1];
  char* ws = (char*)d_ws;
  __hip_bfloat16* An = (__hip_bfloat16*)ws;                              // 12.6 MB
  __hip_bfloat16* Bn = (__hip_bfloat16*)(ws + (size_t)NROWS * DIM * 2);  // 12.6 MB
  unsigned* rowKey = (unsigned*)(ws + (size_t)NROWS * DIM * 4);          // 32 KB
  unsigned* colKey = rowKey + NROWS;                                     // 32 KB

  hipMemsetAsync(rowKey, 0, 2 * NROWS * sizeof(unsigned), stream);
  normalize_kernel<<<2 * NROWS, 256, 0, stream>>>(ex, ey, An, Bn);
  dim3 grid(NROWS / BM, NROWS / BN);
  gemm_max_kernel<<<grid, 512, 0, stream>>>(An, Bn, rowKey, colKey);
  finalize_kernel<<<2, 256, 0, stream>>>(rowKey, colKey, (float*)d_out);
}